// Round 5
// baseline (284.977 us; speedup 1.0000x reference)
//
#include <hip/hip_runtime.h>
#include <cstddef>

#define EPS_ 1e-6f

typedef unsigned short u16;
typedef __attribute__((ext_vector_type(8))) short short8;      // bf16x8 MFMA frag
typedef __attribute__((ext_vector_type(8))) unsigned short us8;
typedef __attribute__((ext_vector_type(4))) unsigned short us4;
typedef __attribute__((ext_vector_type(4))) float f32x4;

__device__ __forceinline__ float sigmoidf_(float x){ return 1.0f/(1.0f+__expf(-x)); }
__device__ __forceinline__ float sigmoidf_fast(float x){
  return __builtin_amdgcn_rcpf(1.0f+__expf(-x));
}
__device__ __forceinline__ u16 f2bf(float x){
  union { __bf16 b; u16 u; } c; c.b = (__bf16)x; return c.u;
}
__device__ __forceinline__ float bf2f(u16 u){
  union { unsigned i; float f; } c; c.i = ((unsigned)u) << 16; return c.f;
}
__device__ __forceinline__ us4 cvt4(float4 v){
  us4 h; h[0]=f2bf(v.x); h[1]=f2bf(v.y); h[2]=f2bf(v.z); h[3]=f2bf(v.w); return h;
}

// ---------------------------------------------------------------------------
// prep_w: emit W in MFMA B-FRAGMENT order (1KB contiguous wave loads).
// WTf[((eb*8+it)*64 + lane)*8 + j] = bf16(W[d][e]),
//   e = eb*16 + (lane&15), d = it*32 + (lane>>4)*8 + j.
// ---------------------------------------------------------------------------
__global__ __launch_bounds__(256) void prep_w(const float* __restrict__ Wq,
                                              const float* __restrict__ Wk,
                                              u16* __restrict__ WqT,
                                              u16* __restrict__ WkT){
  const int m  = blockIdx.x >> 4;
  const int eb = blockIdx.x & 15;
  const float* W = m ? Wk : Wq;
  u16* WTf = m ? WkT : WqT;
  const int t = threadIdx.x;
  #pragma unroll
  for (int rep = 0; rep < 2; rep++) {
    const int lin  = rep*256 + t;
    const int it   = lin >> 6;
    const int lane = lin & 63;
    const int q    = lane >> 4;
    const int i16  = lane & 15;
    us8 o;
    #pragma unroll
    for (int j = 0; j < 8; j++)
      o[j] = f2bf(W[(it*32 + q*8 + j)*256 + eb*16 + i16]);
    *(us8*)&WTf[(size_t)((eb*8 + it)*512 + lane*8)] = o;
  }
}

// ---------------------------------------------------------------------------
// phi_k v3: 4 K-tiles per block (grid 256, 1 block/CU), A double-buffered in
// LDS (separate from T2 region -> no union hazards). Next tile's 16 float4
// loads are issued right after GEMM1; the transpose epilogue (pure VALU/LDS)
// covers the HBM latency; the A-write (the only vmcnt wait) lands afterwards
// and is published by the epilogue's own barriers. Kills the per-tile exposed
// staging stall that capped phi at ~20% HBM.
// ---------------------------------------------------------------------------
__global__ __launch_bounds__(256, 1) void phi_k(
    const float* __restrict__ K, const u16* __restrict__ WkT,
    const float* __restrict__ bk,
    u16* __restrict__ phi_kT, float* __restrict__ colsum)
{
  __shared__ u16 A[2][64][264];    // 67584 B double-buffered staging
  __shared__ u16 T2[128][136];     // 34816 B transpose epilogue

  const int t = threadIdx.x;
  const int l = t & 63;
  const int wf = t >> 6;
  const int i16 = l & 15, q = l >> 4;
  const int base_row = blockIdx.x * 256;
  const int b       = blockIdx.x >> 4;
  const int nc_base = (blockIdx.x & 15) * 4;
  const int r0 = t >> 4, c0 = t & 15;

  float bv[4];
  #pragma unroll
  for (int fi=0;fi<4;fi++) bv[fi] = bk[wf*64 + fi*16 + i16];
  const u16* wbf = WkT + (size_t)wf*16384 + (size_t)l*8;

  float4 v[16];
  {
    const size_t g0 = (size_t)base_row * 256;
    #pragma unroll
    for (int p=0;p<16;p++)
      v[p] = *(const float4*)&K[g0 + (size_t)(r0 + 16*(p>>2))*256 + (c0 + 16*(p&3))*4];
    #pragma unroll
    for (int p=0;p<16;p++)
      *(us4*)&A[0][r0 + 16*(p>>2)][(c0 + 16*(p&3))*4] = cvt4(v[p]);
  }
  __syncthreads();

  for (int tt = 0; tt < 4; ++tt) {
    const int cur = tt & 1, nxt = cur ^ 1;

    // ---- GEMM1: phi_k tile = K_tile @ Wk ----
    f32x4 acc[4][4];
    #pragma unroll
    for (int i=0;i<4;i++)
      #pragma unroll
      for (int j=0;j<4;j++) acc[i][j] = (f32x4){0.f,0.f,0.f,0.f};

    short8 Bfr[3][4];
    #pragma unroll
    for (int fi=0;fi<4;fi++) Bfr[0][fi] = *(const short8*)&wbf[fi*4096];
    #pragma unroll
    for (int fi=0;fi<4;fi++) Bfr[1][fi] = *(const short8*)&wbf[fi*4096 + 512];

    #pragma unroll
    for (int it = 0; it < 8; it++) {
      if (it < 6) {
        #pragma unroll
        for (int fi=0;fi<4;fi++)
          Bfr[(it+2)%3][fi] = *(const short8*)&wbf[fi*4096 + (it+2)*512];
      }
      short8 af[4];
      #pragma unroll
      for (int mi=0;mi<4;mi++)
        af[mi] = *(const short8*)&A[cur][mi*16 + i16][it*32 + q*8];
      #pragma unroll
      for (int mi=0;mi<4;mi++)
        #pragma unroll
        for (int fi=0;fi<4;fi++)
          acc[mi][fi] = __builtin_amdgcn_mfma_f32_16x16x32_bf16(af[mi], Bfr[it%3][fi], acc[mi][fi], 0,0,0);
    }

    // ---- issue next tile's staging loads (stay in flight through epilogue) ----
    if (tt < 3) {
      const size_t g1 = (size_t)(base_row + (tt+1)*64) * 256;
      #pragma unroll
      for (int p=0;p<16;p++)
        v[p] = *(const float4*)&K[g1 + (size_t)(r0 + 16*(p>>2))*256 + (c0 + 16*(p&3))*4];
    }

    const int nchunk = nc_base + tt;

    // ---- transpose epilogue, half 0 (waves 0,1) ----
    if ((wf >> 1) == 0) {
      #pragma unroll
      for (int fi=0;fi<4;fi++) {
        float cp = 0.f;
        #pragma unroll
        for (int mi=0;mi<4;mi++) {
          #pragma unroll
          for (int r=0;r<4;r++) {
            float ph = sigmoidf_fast(acc[mi][fi][r] + bv[fi]);
            cp += ph;
            T2[(wf*64 + fi*16 + i16) & 127][mi*16 + q*4 + r] = f2bf(ph);
          }
        }
        cp += __shfl_xor(cp,16); cp += __shfl_xor(cp,32);
        if (l < 16) atomicAdd(&colsum[b*256 + wf*64 + fi*16 + l], cp);
      }
    }
    __syncthreads();
    {
      const size_t gb = ((size_t)(b*64 + nchunk)*256 + 0*128) * 64;
      #pragma unroll
      for (int j=0;j<4;j++) {
        const int g = (j*256 + t) * 8;
        *(us8*)&phi_kT[gb + g] = *(const us8*)&T2[g >> 6][g & 63];
      }
    }
    __syncthreads();

    // ---- A-write for next tile (v landed during half-0; published by the
    //      half-1 barriers below) ----
    if (tt < 3) {
      #pragma unroll
      for (int p=0;p<16;p++)
        *(us4*)&A[nxt][r0 + 16*(p>>2)][(c0 + 16*(p&3))*4] = cvt4(v[p]);
    }

    // ---- transpose epilogue, half 1 (waves 2,3) ----
    if ((wf >> 1) == 1) {
      #pragma unroll
      for (int fi=0;fi<4;fi++) {
        float cp = 0.f;
        #pragma unroll
        for (int mi=0;mi<4;mi++) {
          #pragma unroll
          for (int r=0;r<4;r++) {
            float ph = sigmoidf_fast(acc[mi][fi][r] + bv[fi]);
            cp += ph;
            T2[(wf*64 + fi*16 + i16) & 127][mi*16 + q*4 + r] = f2bf(ph);
          }
        }
        cp += __shfl_xor(cp,16); cp += __shfl_xor(cp,32);
        if (l < 16) atomicAdd(&colsum[b*256 + wf*64 + fi*16 + l], cp);
      }
    }
    __syncthreads();
    {
      const size_t gb = ((size_t)(b*64 + nchunk)*256 + 1*128) * 64;
      #pragma unroll
      for (int j=0;j<4;j++) {
        const int g = (j*256 + t) * 8;
        *(us8*)&phi_kT[gb + g] = *(const us8*)&T2[g >> 6][g & 63];
      }
    }
    __syncthreads();   // publishes T2 consumption AND A[nxt] for next GEMM1
  }
}

// ---------------------------------------------------------------------------
// KV partials v3: nc split halved 16 -> 8 (8 chunks of 64 n per block):
// partsT traffic halves (33.5 -> 16.8 MB each way). Structure otherwise as
// before: phi_kT tiled reads, E = exp(phi_k*inv_cs*V), fragment-flat stores.
// ---------------------------------------------------------------------------
__global__ __launch_bounds__(256) void kv_kernel(const u16* __restrict__ phi_kT,
    const float* __restrict__ V, const float* __restrict__ colsum,
    u16* __restrict__ partsT, float* __restrict__ denom)
{
  __shared__ u16 phiT_lds[256][72];   // [d][n 64]
  __shared__ u16 E_lds[64][72];       // [e][n 64]

  const int t = threadIdx.x;
  const int l = t & 63;
  const int w = t >> 6;
  const int e0 = blockIdx.x * 64;
  const int nc = blockIdx.y;          // 0..7
  const int b  = blockIdx.z;
  const int i16 = l & 15, q = l >> 4;

  const int sd = t >> 3;
  const int sn = (t & 7) * 8;

  const size_t cbase = (size_t)(b*64 + nc*8) * 16384;   // u16 idx of chunk 0

  us8  rA[8];
  float rV[16];
  #pragma unroll
  for (int p=0;p<8;p++)
    rA[p] = *(const us8*)&phi_kT[cbase + (size_t)(sd + 32*p)*64 + sn];
  #pragma unroll
  for (int j=0;j<16;j++)
    rV[j] = V[(size_t)(b*4096 + nc*512 + w*16 + j)*256 + e0 + l];

  const float inv_cs = 1.0f / (colsum[b*256 + e0 + l] + EPS_);
  float dsum = 0.f;

  f32x4 acc[4][4];
  #pragma unroll
  for (int i=0;i<4;i++)
    #pragma unroll
    for (int j=0;j<4;j++) acc[i][j] = (f32x4){0.f,0.f,0.f,0.f};

  for (int c = 0; c < 8; c++) {
    #pragma unroll
    for (int p=0;p<8;p++) *(us8*)&phiT_lds[sd + 32*p][sn] = rA[p];
    __syncthreads();
    if (c < 7) {
      const size_t nb = cbase + (size_t)(c+1)*16384;
      #pragma unroll
      for (int p=0;p<8;p++)
        rA[p] = *(const us8*)&phi_kT[nb + (size_t)(sd + 32*p)*64 + sn];
    }
    us8 pv0 = *(const us8*)&phiT_lds[e0 + l][w*16];
    us8 pv1 = *(const us8*)&phiT_lds[e0 + l][w*16 + 8];
    us8 ev0, ev1;
    #pragma unroll
    for (int j=0;j<8;j++) {
      float ef = __expf(bf2f(pv0[j]) * inv_cs * rV[j]);
      dsum += ef; ev0[j] = f2bf(ef);
    }
    #pragma unroll
    for (int j=0;j<8;j++) {
      float ef = __expf(bf2f(pv1[j]) * inv_cs * rV[8+j]);
      dsum += ef; ev1[j] = f2bf(ef);
    }
    *(us8*)&E_lds[l][w*16]     = ev0;
    *(us8*)&E_lds[l][w*16 + 8] = ev1;
    if (c < 7) {
      #pragma unroll
      for (int j=0;j<16;j++)
        rV[j] = V[(size_t)(b*4096 + nc*512 + (c+1)*64 + w*16 + j)*256 + e0 + l];
    }
    __syncthreads();
    #pragma unroll
    for (int kk=0;kk<2;kk++){
      const int ko = kk*32 + q*8;
      short8 af[4], bfr[4];
      #pragma unroll
      for (int mi=0;mi<4;mi++) af[mi]  = *(const short8*)&phiT_lds[w*64 + mi*16 + i16][ko];
      #pragma unroll
      for (int ei=0;ei<4;ei++) bfr[ei] = *(const short8*)&E_lds[ei*16 + i16][ko];
      #pragma unroll
      for (int mi=0;mi<4;mi++)
        #pragma unroll
        for (int ei=0;ei<4;ei++)
          acc[mi][ei] = __builtin_amdgcn_mfma_f32_16x16x32_bf16(af[mi], bfr[ei], acc[mi][ei],0,0,0);
    }
    __syncthreads();
  }

  atomicAdd(&denom[b*256 + e0 + l], dsum);

  u16* slice = partsT + (size_t)(nc*16 + b) * 65536 + (size_t)blockIdx.x * 16384;
  #pragma unroll
  for (int mi=0;mi<4;mi++)
    #pragma unroll
    for (int ei=0;ei<4;ei++) {
      us4 o;
      #pragma unroll
      for (int r=0;r<4;r++) o[r] = f2bf(acc[mi][ei][r]);
      *(us4*)&slice[(size_t)(((w*16 + mi*4 + ei)*64 + l)*4)] = o;
    }
}

// ---------------------------------------------------------------------------
// kv_norm: reduce fragment-flat partsT over 8 nc slices, divide by denom,
// emit KV_n in MFMA B-FRAGMENT order.
// ---------------------------------------------------------------------------
__global__ __launch_bounds__(256) void kv_norm(const u16* __restrict__ partsT,
    const float* __restrict__ denom, u16* __restrict__ KV_nT)
{
  const int t = threadIdx.x;
  const int b = blockIdx.y;
  const int s4 = blockIdx.x*256 + t;
  const int e0b = s4 >> 12;
  const int rem = s4 & 4095;
  const int comb = rem >> 6;
  const int l = rem & 63;
  const int w  = comb >> 4;
  const int mi = (comb >> 2) & 3;
  const int ei = comb & 3;
  const int e  = e0b*64 + ei*16 + (l & 15);
  const int d0 = w*64 + mi*16 + (l >> 4)*4;

  const float dn = denom[b*256 + e];
  float s0=0.f,s1=0.f,s2=0.f,s3=0.f;
  #pragma unroll 4
  for (int nc=0;nc<8;nc++){
    us4 v = *(const us4*)&partsT[(size_t)(nc*16 + b)*65536 + (size_t)s4*4];
    s0+=bf2f(v[0]); s1+=bf2f(v[1]); s2+=bf2f(v[2]); s3+=bf2f(v[3]);
  }
  us4 o; o[0]=f2bf(s0/dn); o[1]=f2bf(s1/dn); o[2]=f2bf(s2/dn); o[3]=f2bf(s3/dn);

  const int eb  = e >> 4;
  const int i16 = e & 15;
  const int it  = d0 >> 5;
  const int qo  = (d0 >> 3) & 3;
  const int j0  = d0 & 4;
  *(us4*)&KV_nT[(size_t)b*65536 + (size_t)((eb*8 + it)*512 + (qo*16 + i16)*8 + j0)] = o;
}

// ---------------------------------------------------------------------------
// out_fused v2: 4 n-tiles per block (grid 256 = 1 block/CU). A double-buffered
// (separate from S -> no union barrier coupling). Per tile:
//   GEMM1(A[cur]) -> issue next Q loads -> epilogue1 (VALU/LDS, covers HBM
//   latency) -> A[nxt] write (vmcnt wait, loads landed) -> barrier ->
//   GEMM2(S) -> gate+store -> barrier.  2 barriers/tile; rs double-buffered.
// ---------------------------------------------------------------------------
__global__ __launch_bounds__(256, 1) void out_fused(
    const float* __restrict__ Q, const u16* __restrict__ WqT,
    const float* __restrict__ bq, const u16* __restrict__ KV_nT,
    float* __restrict__ outp)
{
  __shared__ u16 A[2][64][264];    // 67584 B
  __shared__ u16 S[64][264];       // 33792 B
  __shared__ float rs_sh[2][64];

  const int t = threadIdx.x;
  const int l = t & 63;
  const int wf = t >> 6;
  const int i16 = l & 15, q = l >> 4;
  const int n_base = blockIdx.x * 256;
  const int b  = blockIdx.y;
  const int r0 = t >> 4, c0 = t & 15;

  float bv[4];
  #pragma unroll
  for (int fi=0;fi<4;fi++) bv[fi] = bq[wf*64 + fi*16 + i16];
  const u16* wbf = WqT + (size_t)wf*16384 + (size_t)l*8;
  const u16* kbf = KV_nT + (size_t)b*65536 + (size_t)wf*16384 + (size_t)l*8;

  if (t < 64) rs_sh[0][t] = 0.f;

  float4 v[16];
  {
    const size_t g0 = (size_t)(b*4096 + n_base) * 256;
    #pragma unroll
    for (int p=0;p<16;p++)
      v[p] = *(const float4*)&Q[g0 + (size_t)(r0 + 16*(p>>2))*256 + (c0 + 16*(p&3))*4];
    #pragma unroll
    for (int p=0;p<16;p++)
      *(us4*)&A[0][r0 + 16*(p>>2)][(c0 + 16*(p&3))*4] = cvt4(v[p]);
  }
  __syncthreads();

  for (int tt = 0; tt < 4; ++tt) {
    const int cur = tt & 1, nxt = cur ^ 1;
    const int n0 = n_base + tt*64;

    // ---- GEMM1: phi = Q_tile @ Wq ----
    f32x4 acc[4][4];
    #pragma unroll
    for (int i=0;i<4;i++)
      #pragma unroll
      for (int j=0;j<4;j++) acc[i][j] = (f32x4){0.f,0.f,0.f,0.f};

    {
      short8 Bfr[3][4];
      #pragma unroll
      for (int fi=0;fi<4;fi++) Bfr[0][fi] = *(const short8*)&wbf[fi*4096];
      #pragma unroll
      for (int fi=0;fi<4;fi++) Bfr[1][fi] = *(const short8*)&wbf[fi*4096 + 512];

      #pragma unroll
      for (int it = 0; it < 8; it++) {
        if (it < 6) {
          #pragma unroll
          for (int fi=0;fi<4;fi++)
            Bfr[(it+2)%3][fi] = *(const short8*)&wbf[fi*4096 + (it+2)*512];
        }
        short8 af[4];
        #pragma unroll
        for (int mi=0;mi<4;mi++)
          af[mi] = *(const short8*)&A[cur][mi*16 + i16][it*32 + q*8];
        #pragma unroll
        for (int mi=0;mi<4;mi++)
          #pragma unroll
          for (int fi=0;fi<4;fi++)
            acc[mi][fi] = __builtin_amdgcn_mfma_f32_16x16x32_bf16(af[mi], Bfr[it%3][fi], acc[mi][fi], 0,0,0);
      }
    }

    // ---- issue next tile's Q loads (in flight through epilogue1) ----
    if (tt < 3) {
      const size_t g1 = (size_t)(b*4096 + n0 + 64) * 256;
      #pragma unroll
      for (int p=0;p<16;p++)
        v[p] = *(const float4*)&Q[g1 + (size_t)(r0 + 16*(p>>2))*256 + (c0 + 16*(p&3))*4];
    }

    // ---- epilogue1: sigmoid -> S + block-local rowsum (pure VALU/LDS) ----
    #pragma unroll
    for (int mi=0;mi<4;mi++) {
      float rsub[4] = {0.f,0.f,0.f,0.f};
      #pragma unroll
      for (int fi=0;fi<4;fi++) {
        #pragma unroll
        for (int r=0;r<4;r++) {
          float ph = sigmoidf_fast(acc[mi][fi][r] + bv[fi]);
          rsub[r] += ph;
          S[mi*16 + q*4 + r][wf*64 + fi*16 + i16] = f2bf(ph);
        }
      }
      #pragma unroll
      for (int r=0;r<4;r++) {
        float s = rsub[r];
        s += __shfl_xor(s,1); s += __shfl_xor(s,2); s += __shfl_xor(s,4); s += __shfl_xor(s,8);
        if (i16 == 0) atomicAdd(&rs_sh[cur][mi*16 + q*4 + r], s);
      }
    }

    // ---- A[nxt] write (loads landed during epilogue1) + rs[nxt] zero ----
    if (tt < 3) {
      #pragma unroll
      for (int p=0;p<16;p++)
        *(us4*)&A[nxt][r0 + 16*(p>>2)][(c0 + 16*(p&3))*4] = cvt4(v[p]);
    }
    if (t < 64) rs_sh[nxt][t] = 0.f;

    // GEMM2 B prefetch (overlaps barrier wait)
    short8 Bf2[3][4];
    #pragma unroll
    for (int ei=0;ei<4;ei++) Bf2[0][ei] = *(const short8*)&kbf[ei*4096];
    #pragma unroll
    for (int ei=0;ei<4;ei++) Bf2[1][ei] = *(const short8*)&kbf[ei*4096 + 512];

    __syncthreads();   // publish S, rs[cur], A[nxt], rs[nxt]=0

    // ---- GEMM2: out = gate * phi @ KV ----
    #pragma unroll
    for (int i=0;i<4;i++)
      #pragma unroll
      for (int j=0;j<4;j++) acc[i][j] = (f32x4){0.f,0.f,0.f,0.f};

    #pragma unroll
    for (int it=0; it<8; it++){
      if (it < 6) {
        #pragma unroll
        for (int ei=0;ei<4;ei++)
          Bf2[(it+2)%3][ei] = *(const short8*)&kbf[ei*4096 + (it+2)*512];
      }
      short8 af[4];
      #pragma unroll
      for (int mi=0;mi<4;mi++)
        af[mi] = *(const short8*)&S[mi*16 + i16][it*32 + q*8];
      #pragma unroll
      for (int mi=0;mi<4;mi++)
        #pragma unroll
        for (int ei=0;ei<4;ei++)
          acc[mi][ei] = __builtin_amdgcn_mfma_f32_16x16x32_bf16(af[mi], Bf2[it%3][ei], acc[mi][ei],0,0,0);
    }

    #pragma unroll
    for (int mi=0;mi<4;mi++){
      #pragma unroll
      for (int r=0;r<4;r++){
        const int nl = mi*16 + q*4 + r;
        const float rs = rs_sh[cur][nl];
        const float gate = sigmoidf_(rs) / (rs + EPS_);
        #pragma unroll
        for (int ei=0;ei<4;ei++)
          outp[((size_t)(b*4096 + n0 + nl))*256 + wf*64 + ei*16 + i16] = gate*acc[mi][ei][r];
      }
    }
    __syncthreads();   // S / rs[cur] reads done
  }
}

extern "C" void kernel_launch(void* const* d_in, const int* in_sizes, int n_in,
                              void* d_out, int out_size, void* d_ws, size_t ws_size,
                              hipStream_t stream) {
  const float* Q  = (const float*)d_in[0];
  const float* K  = (const float*)d_in[1];
  const float* V  = (const float*)d_in[2];
  const float* Wq = (const float*)d_in[3];
  const float* bq = (const float*)d_in[4];
  const float* Wk = (const float*)d_in[5];
  const float* bk = (const float*)d_in[6];
  float* out = (float*)d_out;

  u16* phi_kT = (u16*)d_ws;                 // 16,777,216 bf16 TILED [b][nchunk][d][n64]
  u16* WqT    = phi_kT + 16777216;          // 65,536 (fragment order)
  u16* WkT    = WqT + 65536;                // 65,536 (fragment order)
  float* colsum = (float*)(WkT + 65536);    // 4096
  float* denom  = colsum + 4096;            // 4096
  u16* partsT = (u16*)(denom + 4096);       // 8*16*65536 bf16 (fragment-flat)
  u16* KV_nT  = partsT + 8388608;           // 1,048,576 bf16 (fragment order)

  hipMemsetAsync(colsum, 0, 8192 * sizeof(float), stream);

  prep_w<<<dim3(32), 256, 0, stream>>>(Wq, Wk, WqT, WkT);
  phi_k<<<dim3(256), 256, 0, stream>>>(K, WkT, bk, phi_kT, colsum);
  kv_kernel<<<dim3(4, 8, 16), 256, 0, stream>>>(phi_kT, V, colsum, partsT, denom);
  kv_norm<<<dim3(64, 16), 256, 0, stream>>>(partsT, denom, KV_nT);
  out_fused<<<dim3(16, 16), 256, 0, stream>>>(Q, WqT, bq, KV_nT, out);
}